// Round 7
// baseline (519.658 us; speedup 1.0000x reference)
//
#include <hip/hip_runtime.h>

static constexpr int NE   = 4096;      // n_embed
static constexpr int ED   = 64;        // embed_dim
static constexpr int NTOK = 65536;     // 4*16*32*32
static constexpr int NCHUNK = 16;      // code-loop split factor
static constexpr int CPC  = NE / NCHUNK;   // codes per chunk = 256

typedef float f32x2 __attribute__((ext_vector_type(2)));

// packed fp32 fma (used in the A-sum preamble; per-lane == fmaf exactly)
static __device__ __forceinline__ f32x2 pkfma(f32x2 a, f32x2 b, f32x2 c) {
#if __has_builtin(__builtin_elementwise_fma)
    return __builtin_elementwise_fma(a, b, c);
#else
    f32x2 r;
    r.x = fmaf(a.x, b.x, c.x);
    r.y = fmaf(a.y, b.y, c.y);
    return r;
#endif
}

// d_out offsets (float elements), outputs concatenated in return order:
// out(4194304), loss(1), perplexity(1), idx(65536), new_embed(262144),
// new_cs(4096), new_ea(262144)
static constexpr long O_OUT  = 0;
static constexpr long O_LOSS = 4194304;
static constexpr long O_PERP = 4194305;
static constexpr long O_IDX  = 4194306;
static constexpr long O_NEMB = 4259842;
static constexpr long O_NCS  = 4521986;
static constexpr long O_NEA  = 4526082;

// ws layout (bytes)
static constexpr size_t W_ACC   = 0;        // double[4]: [0]=loss [1]=n [2]=plog   (zeroed)
static constexpr size_t W_CNT   = 32;       // unsigned[4096] counts                (zeroed)
static constexpr size_t W_CUR   = 16416;    // unsigned[4096] scatter cursors       (zeroed)
static constexpr size_t W_OFF   = 32800;    // unsigned[4096] bucket start offsets
static constexpr size_t W_BSQ   = 49184;    // float[4096]  ||e_n||^2
static constexpr size_t W_IDX   = 65568;    // int[65536]
static constexpr size_t W_BKT   = 327712;   // int[65536] token ids bucketed by code
static constexpr size_t W_LOSSP = 589856;   // double[16384] per-block loss partials
static constexpr size_t W_PKD   = 720928;   // uint64[65536] packed (d_bits<<32)|idx
static constexpr size_t W_ZERO_BYTES = 32800;   // acc + counts + cursors
static constexpr size_t W_PKD_BYTES  = 524288;  // 0xFF-init packed

// ---- ||e_n||^2 precompute -------------------------------------------------
__global__ __launch_bounds__(256) void kBsq(const float* __restrict__ e,
                                            float* __restrict__ bsq) {
    int n = blockIdx.x * 256 + threadIdx.x;
    const float* er = e + (n << 6);
    float a0 = 0.f, a1 = 0.f, a2 = 0.f, a3 = 0.f;
#pragma unroll
    for (int k = 0; k < ED; k += 4) {
        a0 = fmaf(er[k+0], er[k+0], a0);
        a1 = fmaf(er[k+1], er[k+1], a1);
        a2 = fmaf(er[k+2], er[k+2], a2);
        a3 = fmaf(er[k+3], er[k+3], a3);
    }
    bsq[n] = (a0 + a1) + (a2 + a3);
}

// 32 named f32x2 registers Z0..Z31
#define Z_EACH(F) \
    F(0)  F(1)  F(2)  F(3)  F(4)  F(5)  F(6)  F(7)  \
    F(8)  F(9)  F(10) F(11) F(12) F(13) F(14) F(15) \
    F(16) F(17) F(18) F(19) F(20) F(21) F(22) F(23) \
    F(24) F(25) F(26) F(27) F(28) F(29) F(30) F(31)

// E-row lives in fixed SGPRs s[32:95] (dword i = e[dim i]); declared as
// clobbers on EVERY asm block so the compiler never allocates values across
// them (it only needs ~30 SGPRs of its own -> fits s0..s31 + s96+).
#define ECLOBBERS \
    "s32","s33","s34","s35","s36","s37","s38","s39", \
    "s40","s41","s42","s43","s44","s45","s46","s47", \
    "s48","s49","s50","s51","s52","s53","s54","s55", \
    "s56","s57","s58","s59","s60","s61","s62","s63", \
    "s64","s65","s66","s67","s68","s69","s70","s71", \
    "s72","s73","s74","s75","s76","s77","s78","s79", \
    "s80","s81","s82","s83","s84","s85","s86","s87", \
    "s88","s89","s90","s91","s92","s93","s94","s95"

// One packed FMA line: acc op0/op1 alternate (even pair J -> c0, odd -> c1),
// sgpr pair = s[32+2J : 32+2J+1]. Numerics: per-lane IEEE fma == fmaf, and
// the even/odd split in ascending J order reproduces the exact 4-partial
// (d0..d3) fp32 dot of the r4-r6 passing kernels bit-identically.
#define PKLINE(ACC, ZOP, SLO, SHI) \
    "v_pk_fma_f32 %[" ACC "], %[" ZOP "], s[" #SLO ":" #SHI "], %[" ACC "]\n\t"

// ---- argmin over a 256-code chunk, one thread per token -------------------
// grid = 4096 blocks: block = (tokenBlock<<4) | chunk
// r6 post-mortem: allocator parks the 64 z-floats in AGPRs no matter what
// (VGPR_Count=40 across r4-r6); scalar v_fma can read AGPRs directly but
// v_pk_fma cannot -> scalarized dot (~100 VALU insts/iter). Fix: inline-asm
// inner loop; "v" constraints force true VGPR residency and emit 32
// v_pk_fma_f32; e-row via our own s_load_dwordx16 x4 into fixed s[32:95].
__global__ __launch_bounds__(256, 4) void kArgmin(const float* __restrict__ z,
                                                  const float* __restrict__ e,
                                                  const float* __restrict__ bsq,
                                                  unsigned long long* __restrict__ packed) {
    int bid = blockIdx.x;
    int tb = bid >> 4;
    int chunk = bid & 15;
    int t = tb * 256 + threadIdx.x;             // token id
    int b = t >> 14;                            // batch
    int s = t & 16383;                          // d*1024+h*32+w
    const float* zp = z + (long)b * 1048576 + s;

    // ZJ = (z[2J], z[2J+1])
#define Z_LOAD(J) f32x2 Z##J; Z##J.x = zp[(2*J)   * 16384]; \
                              Z##J.y = zp[(2*J+1) * 16384];
    Z_EACH(Z_LOAD)
#undef Z_LOAD

    // A = sum z^2: aa0 accumulates even pairs (k%4 in {0,1}), aa1 odd ({2,3})
    f32x2 aa0 = {0.f, 0.f}, aa1 = {0.f, 0.f};
#define Z_ASUM(J) { if ((J & 1) == 0) aa0 = pkfma(Z##J, Z##J, aa0); \
                    else              aa1 = pkfma(Z##J, Z##J, aa1); }
    Z_EACH(Z_ASUM)
#undef Z_ASUM
    float A = (aa0.x + aa0.y) + (aa1.x + aa1.y);   // == (a0+a1)+(a2+a3)

    float best = __builtin_inff();
    int bidx = 0;
    int c0 = chunk * CPC;
#pragma unroll 1
    for (int n = c0; n < c0 + CPC; ++n) {
        // wave-uniform row address for scalar (SMEM) codebook fetch
        int nu = __builtin_amdgcn_readfirstlane(n);
        const float* er = e + (nu << 6);
        float bq = bsq[nu];

        // 256B e-row -> s[32:95]
        asm volatile(
            "s_load_dwordx16 s[32:47], %[ba], 0x0\n\t"
            "s_load_dwordx16 s[48:63], %[ba], 0x40\n\t"
            "s_load_dwordx16 s[64:79], %[ba], 0x80\n\t"
            "s_load_dwordx16 s[80:95], %[ba], 0xc0\n\t"
            :
            : [ba]"s"(er)
            : ECLOBBERS);

        f32x2 c0v = {0.f, 0.f}, c1v = {0.f, 0.f};
        asm volatile(
            "s_waitcnt lgkmcnt(0)\n\t"
            PKLINE("c0", "z0", 32, 33)
            PKLINE("c1", "z1", 34, 35)
            PKLINE("c0", "z2", 36, 37)
            PKLINE("c1", "z3", 38, 39)
            PKLINE("c0", "z4", 40, 41)
            PKLINE("c1", "z5", 42, 43)
            PKLINE("c0", "z6", 44, 45)
            PKLINE("c1", "z7", 46, 47)
            : [c0]"+v"(c0v), [c1]"+v"(c1v)
            : [z0]"v"(Z0), [z1]"v"(Z1), [z2]"v"(Z2), [z3]"v"(Z3),
              [z4]"v"(Z4), [z5]"v"(Z5), [z6]"v"(Z6), [z7]"v"(Z7)
            : ECLOBBERS);
        asm volatile(
            PKLINE("c0", "z0", 48, 49)
            PKLINE("c1", "z1", 50, 51)
            PKLINE("c0", "z2", 52, 53)
            PKLINE("c1", "z3", 54, 55)
            PKLINE("c0", "z4", 56, 57)
            PKLINE("c1", "z5", 58, 59)
            PKLINE("c0", "z6", 60, 61)
            PKLINE("c1", "z7", 62, 63)
            : [c0]"+v"(c0v), [c1]"+v"(c1v)
            : [z0]"v"(Z8), [z1]"v"(Z9), [z2]"v"(Z10), [z3]"v"(Z11),
              [z4]"v"(Z12), [z5]"v"(Z13), [z6]"v"(Z14), [z7]"v"(Z15)
            : ECLOBBERS);
        asm volatile(
            PKLINE("c0", "z0", 64, 65)
            PKLINE("c1", "z1", 66, 67)
            PKLINE("c0", "z2", 68, 69)
            PKLINE("c1", "z3", 70, 71)
            PKLINE("c0", "z4", 72, 73)
            PKLINE("c1", "z5", 74, 75)
            PKLINE("c0", "z6", 76, 77)
            PKLINE("c1", "z7", 78, 79)
            : [c0]"+v"(c0v), [c1]"+v"(c1v)
            : [z0]"v"(Z16), [z1]"v"(Z17), [z2]"v"(Z18), [z3]"v"(Z19),
              [z4]"v"(Z20), [z5]"v"(Z21), [z6]"v"(Z22), [z7]"v"(Z23)
            : ECLOBBERS);
        asm volatile(
            PKLINE("c0", "z0", 80, 81)
            PKLINE("c1", "z1", 82, 83)
            PKLINE("c0", "z2", 84, 85)
            PKLINE("c1", "z3", 86, 87)
            PKLINE("c0", "z4", 88, 89)
            PKLINE("c1", "z5", 90, 91)
            PKLINE("c0", "z6", 92, 93)
            PKLINE("c1", "z7", 94, 95)
            : [c0]"+v"(c0v), [c1]"+v"(c1v)
            : [z0]"v"(Z24), [z1]"v"(Z25), [z2]"v"(Z26), [z3]"v"(Z27),
              [z4]"v"(Z28), [z5]"v"(Z29), [z6]"v"(Z30), [z7]"v"(Z31)
            : ECLOBBERS);

        float dot = (c0v.x + c0v.y) + (c1v.x + c1v.y);  // == (d0+d1)+(d2+d3)
        // d = fl((A+bq) - 2*dot): 2*dot exact, single-rounding fma == 2-op ref
        float d = fmaf(-2.0f, dot, A + bq);
        if (d < best) { best = d; bidx = n; }   // strict < == first-index ties
    }
    // d >= 0 always so float order == uint order; low 32 bits = idx so
    // equal-d ties pick the smaller index (first-occurrence argmin).
    unsigned long long pk =
        ((unsigned long long)__float_as_uint(best) << 32) | (unsigned)bidx;
    atomicMin(&packed[t], pk);
}

// ---- unpack chunk-combined argmin, emit idx + counts ----------------------
__global__ __launch_bounds__(256) void kFinish(const unsigned long long* __restrict__ packed,
                                               float* __restrict__ outIdxF,
                                               int* __restrict__ wsIdx,
                                               unsigned* __restrict__ counts) {
    int t = blockIdx.x * 256 + threadIdx.x;
    int idx = (int)(unsigned)(packed[t] & 0xFFFFFFFFull);
    outIdxF[t] = (float)idx;
    wsIdx[t]   = idx;
    atomicAdd(&counts[idx], 1u);
}

// ---- exclusive prefix sum of counts -> bucket offsets ---------------------
__global__ __launch_bounds__(256) void kOffsets(const unsigned* __restrict__ counts,
                                                unsigned* __restrict__ offsets) {
    __shared__ unsigned psum[256];
    int tid = threadIdx.x;
    unsigned local[16];
    unsigned s = 0;
#pragma unroll
    for (int j = 0; j < 16; ++j) { local[j] = s; s += counts[tid * 16 + j]; }
    psum[tid] = s;
    __syncthreads();
    unsigned base = 0;
    for (int i = 0; i < tid; ++i) base += psum[i];
#pragma unroll
    for (int j = 0; j < 16; ++j) offsets[tid * 16 + j] = base + local[j];
}

// ---- scatter token ids into per-code buckets ------------------------------
__global__ __launch_bounds__(256) void kScatter(const int* __restrict__ wsIdx,
                                                const unsigned* __restrict__ offsets,
                                                unsigned* __restrict__ cursor,
                                                int* __restrict__ bucket) {
    int t = blockIdx.x * 256 + threadIdx.x;
    int idx = wsIdx[t];
    unsigned pos = atomicAdd(&cursor[idx], 1u);
    bucket[offsets[idx] + pos] = t;
}

// ---- streaming epilogue: gather, straight-through out, loss partials ------
__global__ __launch_bounds__(256) void kEpilogue(const float* __restrict__ z,
                                                 const float* __restrict__ e,
                                                 const int* __restrict__ wsIdx,
                                                 float* __restrict__ out,
                                                 double* __restrict__ lossPart) {
    __shared__ double lp[4];
    long g = (long)blockIdx.x * 256 + threadIdx.x;   // 0 .. 4194303 (z-linear)
    int b = (int)(g >> 20);
    int r = (int)(g & 1048575);
    int k = r >> 14;
    int s = r & 16383;
    int t = (b << 14) | s;

    float zv = z[g];
    int n = wsIdx[t];
    float eq = e[(n << 6) + k];
    float diff = eq - zv;            // fl(z_q - zp)
    out[g] = zv + diff;              // fl(zp + fl(z_q - zp))  (straight-through)

    double sq = (double)diff * (double)diff;
#pragma unroll
    for (int o = 32; o > 0; o >>= 1) sq += __shfl_down(sq, o);
    if ((threadIdx.x & 63) == 0) lp[threadIdx.x >> 6] = sq;
    __syncthreads();
    if (threadIdx.x == 0) lossPart[blockIdx.x] = (lp[0] + lp[1]) + (lp[2] + lp[3]);
}

// ---- reduce loss partials -------------------------------------------------
__global__ __launch_bounds__(256) void kLoss(const double* __restrict__ lossPart,
                                             double* __restrict__ acc) {
    __shared__ double lp[4];
    double s = 0.0;
    for (int j = 0; j < 64; ++j) s += lossPart[threadIdx.x + j * 256];
#pragma unroll
    for (int o = 32; o > 0; o >>= 1) s += __shfl_down(s, o);
    if ((threadIdx.x & 63) == 0) lp[threadIdx.x >> 6] = s;
    __syncthreads();
    if (threadIdx.x == 0) acc[0] = (lp[0] + lp[1]) + (lp[2] + lp[3]);
}

// ---- EMA part 1: new_cs, n-sum, perplexity partial ------------------------
__global__ __launch_bounds__(256) void kEma1(const float* __restrict__ cs,
                                             const unsigned* __restrict__ counts,
                                             float* __restrict__ outNcs,
                                             double* __restrict__ acc) {
    int n = blockIdx.x * 256 + threadIdx.x;
    float cf = (float)counts[n];
    float p1 = cs[n] * 0.99f;
    float p2 = 0.01f * cf;
    float ncs = p1 + p2;
    outNcs[n] = ncs;
    float p = cf * (1.0f / 65536.0f);          // exact (pow2 divide)
    float term = p * logf(p + 1e-10f);
    double dn = (double)ncs, dt = (double)term;
#pragma unroll
    for (int o = 32; o > 0; o >>= 1) { dn += __shfl_down(dn, o); dt += __shfl_down(dt, o); }
    if ((threadIdx.x & 63) == 0) {
        atomicAdd(&acc[1], dn);
        atomicAdd(&acc[2], dt);
    }
}

// ---- per-code bucket gather: embed_sum -> new_ea, new_embed; scalars ------
__global__ __launch_bounds__(64) void kEsumEma2(const float* __restrict__ z,
                                                const float* __restrict__ ea,
                                                const int* __restrict__ bucket,
                                                const unsigned* __restrict__ offsets,
                                                const unsigned* __restrict__ counts,
                                                const float* __restrict__ ncsArr,
                                                const double* __restrict__ acc,
                                                float* __restrict__ outNemb,
                                                float* __restrict__ outNea,
                                                float* __restrict__ outLoss,
                                                float* __restrict__ outPerp) {
    int n = blockIdx.x;              // code id
    int k = threadIdx.x;             // dim
    unsigned off = offsets[n];
    unsigned cnt = counts[n];
    float es = 0.f;
    for (unsigned i = 0; i < cnt; ++i) {
        int t = bucket[off + i];
        int b = t >> 14;
        int s = t & 16383;
        es += z[(long)b * 1048576 + k * 16384 + s];
    }
    float nea = ea[(n << 6) + k] * 0.99f + 0.01f * es;
    outNea[(n << 6) + k] = nea;
    float nt = (float)acc[1];
    float ncs = ncsArr[n];
    float sc = ((ncs + 1e-5f) / (nt + 0.04096f)) * nt;
    outNemb[(n << 6) + k] = nea / sc;
    if (n == 0 && k == 0) {
        double m = acc[0] / 4194304.0;
        outLoss[0] = 0.25f * (float)m;
        outPerp[0] = (float)exp(-acc[2]);
    }
}

extern "C" void kernel_launch(void* const* d_in, const int* in_sizes, int n_in,
                              void* d_out, int out_size, void* d_ws, size_t ws_size,
                              hipStream_t stream) {
    const float* z  = (const float*)d_in[0];
    const float* ew = (const float*)d_in[1];
    const float* cs = (const float*)d_in[2];
    const float* ea = (const float*)d_in[3];
    float* out = (float*)d_out;
    char* ws = (char*)d_ws;

    double*   acc    = (double*)(ws + W_ACC);
    unsigned* counts = (unsigned*)(ws + W_CNT);
    unsigned* cursor = (unsigned*)(ws + W_CUR);
    unsigned* offs   = (unsigned*)(ws + W_OFF);
    float*    bsq    = (float*)(ws + W_BSQ);
    int*      wsIdx  = (int*)(ws + W_IDX);
    int*      bucket = (int*)(ws + W_BKT);
    double*   lossP  = (double*)(ws + W_LOSSP);
    unsigned long long* packed = (unsigned long long*)(ws + W_PKD);

    hipMemsetAsync(ws, 0, W_ZERO_BYTES, stream);
    hipMemsetAsync(ws + W_PKD, 0xFF, W_PKD_BYTES, stream);
    kBsq<<<NE / 256, 256, 0, stream>>>(ew, bsq);
    kArgmin<<<(NTOK / 256) * NCHUNK, 256, 0, stream>>>(z, ew, bsq, packed);
    kFinish<<<NTOK / 256, 256, 0, stream>>>(packed, out + O_IDX, wsIdx, counts);
    kOffsets<<<1, 256, 0, stream>>>(counts, offs);
    kScatter<<<NTOK / 256, 256, 0, stream>>>(wsIdx, offs, cursor, bucket);
    kEpilogue<<<16384, 256, 0, stream>>>(z, ew, wsIdx, out + O_OUT, lossP);
    kLoss<<<1, 256, 0, stream>>>(lossP, acc);
    kEma1<<<NE / 256, 256, 0, stream>>>(cs, counts, out + O_NCS, acc);
    kEsumEma2<<<NE, 64, 0, stream>>>(z, ea, bucket, offs, counts, out + O_NCS, acc,
                                     out + O_NEMB, out + O_NEA,
                                     out + O_LOSS, out + O_PERP);
}

// Round 8
// 510.982 us; speedup vs baseline: 1.0170x; 1.0170x over previous
//
#include <hip/hip_runtime.h>

static constexpr int NE   = 4096;      // n_embed
static constexpr int ED   = 64;        // embed_dim
static constexpr int NTOK = 65536;     // 4*16*32*32
static constexpr int NCHUNK = 16;      // code-loop split factor
static constexpr int CPC  = NE / NCHUNK;   // codes per chunk = 256

typedef float  f32x2 __attribute__((ext_vector_type(2)));
typedef float  f32x4 __attribute__((ext_vector_type(4)));

// packed fp32 fma (A-sum preamble only; per-lane == fmaf exactly)
static __device__ __forceinline__ f32x2 pkfma(f32x2 a, f32x2 b, f32x2 c) {
#if __has_builtin(__builtin_elementwise_fma)
    return __builtin_elementwise_fma(a, b, c);
#else
    f32x2 r;
    r.x = fmaf(a.x, b.x, c.x);
    r.y = fmaf(a.y, b.y, c.y);
    return r;
#endif
}

// d_out offsets (float elements), outputs concatenated in return order:
// out(4194304), loss(1), perplexity(1), idx(65536), new_embed(262144),
// new_cs(4096), new_ea(262144)
static constexpr long O_OUT  = 0;
static constexpr long O_LOSS = 4194304;
static constexpr long O_PERP = 4194305;
static constexpr long O_IDX  = 4194306;
static constexpr long O_NEMB = 4259842;
static constexpr long O_NCS  = 4521986;
static constexpr long O_NEA  = 4526082;

// ws layout (bytes)
static constexpr size_t W_ACC   = 0;        // double[4]: [0]=loss [1]=n [2]=plog   (zeroed)
static constexpr size_t W_CNT   = 32;       // unsigned[4096] counts                (zeroed)
static constexpr size_t W_CUR   = 16416;    // unsigned[4096] scatter cursors       (zeroed)
static constexpr size_t W_OFF   = 32800;    // unsigned[4096] bucket start offsets
static constexpr size_t W_IDX   = 49184;    // int[65536]
static constexpr size_t W_BKT   = 311328;   // int[65536] token ids bucketed by code
static constexpr size_t W_LOSSP = 573472;   // double[16384] per-block loss partials
static constexpr size_t W_PKD   = 704544;   // uint64[65536] packed (d_bits<<32)|idx
static constexpr size_t W_AUG   = 1228832;  // float[4096*68]: [e row (64), bq, pad(3)]
static constexpr size_t W_ZERO_BYTES = 32800;   // acc + counts + cursors
static constexpr size_t W_PKD_BYTES  = 524288;  // 0xFF-init packed

// ---- augmented codebook: row n = [e_n[0..63], ||e_n||^2, pad] (stride 68) --
__global__ __launch_bounds__(256) void kAug(const float* __restrict__ e,
                                            float* __restrict__ aug) {
    int n = blockIdx.x * 256 + threadIdx.x;        // 0..4095
    const float* er = e + (n << 6);
    float* row = aug + (long)n * 68;
    // bq numerics: identical fmaf 4-partial chain to the 7x-passing kBsq
    float a0 = 0.f, a1 = 0.f, a2 = 0.f, a3 = 0.f;
#pragma unroll
    for (int k = 0; k < ED; k += 4) {
        a0 = fmaf(er[k+0], er[k+0], a0);
        a1 = fmaf(er[k+1], er[k+1], a1);
        a2 = fmaf(er[k+2], er[k+2], a2);
        a3 = fmaf(er[k+3], er[k+3], a3);
    }
#pragma unroll
    for (int k = 0; k < 16; ++k)
        ((f32x4*)row)[k] = ((const f32x4*)er)[k];
    row[64] = (a0 + a1) + (a2 + a3);
}

// 32 named f32x2 registers Z0..Z31
#define Z_EACH(F) \
    F(0)  F(1)  F(2)  F(3)  F(4)  F(5)  F(6)  F(7)  \
    F(8)  F(9)  F(10) F(11) F(12) F(13) F(14) F(15) \
    F(16) F(17) F(18) F(19) F(20) F(21) F(22) F(23) \
    F(24) F(25) F(26) F(27) F(28) F(29) F(30) F(31)

// Fixed SGPRs inside the single asm loop: s[32:95] e-row, s96 bq,
// s97 n-counter, s[98:99] row pointer, s100 loop end.
#define SCLOBBERS \
    "s32","s33","s34","s35","s36","s37","s38","s39", \
    "s40","s41","s42","s43","s44","s45","s46","s47", \
    "s48","s49","s50","s51","s52","s53","s54","s55", \
    "s56","s57","s58","s59","s60","s61","s62","s63", \
    "s64","s65","s66","s67","s68","s69","s70","s71", \
    "s72","s73","s74","s75","s76","s77","s78","s79", \
    "s80","s81","s82","s83","s84","s85","s86","s87", \
    "s88","s89","s90","s91","s92","s93","s94","s95", \
    "s96","s97","s98","s99","s100"

// ---- argmin over a 256-code chunk, one thread per token -------------------
// grid = 4096 blocks: block = (tokenBlock<<4) | chunk
// r7 post-mortem: per-8-pair asm blocks only force VGPR residency at block
// entry; the allocator kept z's HOME in AGPRs and copied 64 regs per
// code-iter (~100 VALU insts/iter, unchanged r4-r7). Fix: the ENTIRE code
// loop is ONE asm block -> z operands must hold arch VGPRs for the whole
// loop; copies (if any) amortize to once per token.
__global__ __launch_bounds__(256, 4) void kArgmin(const float* __restrict__ z,
                                                  const float* __restrict__ aug,
                                                  unsigned long long* __restrict__ packed) {
    int bid = blockIdx.x;
    int tb = bid >> 4;
    int chunk = bid & 15;
    int t = tb * 256 + threadIdx.x;             // token id
    int b = t >> 14;                            // batch
    int s = t & 16383;                          // d*1024+h*32+w
    const float* zp = z + (long)b * 1048576 + s;

    // ZJ = (z[2J], z[2J+1]) -> pk lanes reproduce the exact 4-partial fp32
    // dot (d0..d3 over k%4, k+=4) of the reference path, bit-identically.
#define Z_LOAD(J) f32x2 Z##J; Z##J.x = zp[(2*J)   * 16384]; \
                              Z##J.y = zp[(2*J+1) * 16384];
    Z_EACH(Z_LOAD)
#undef Z_LOAD

    // A = sum z^2: aa0 accumulates even pairs (k%4 in {0,1}), aa1 odd ({2,3})
    f32x2 aa0 = {0.f, 0.f}, aa1 = {0.f, 0.f};
#define Z_ASUM(J) { if ((J & 1) == 0) aa0 = pkfma(Z##J, Z##J, aa0); \
                    else              aa1 = pkfma(Z##J, Z##J, aa1); }
    Z_EACH(Z_ASUM)
#undef Z_ASUM
    float A = (aa0.x + aa0.y) + (aa1.x + aa1.y);   // == (a0+a1)+(a2+a3)

    int c0i = chunk * CPC;
    int cend = c0i + CPC;
    const float* rowPtr = aug + (long)c0i * 68;

    float best = __builtin_inff();
    int bidx = c0i;

    // Per iter: 4x s_load_dwordx16 (e-row) + s_load_dword (bq) from the
    // augmented table; 32 v_pk_fma/mul (even pair J -> v[48:49]=(d0,d1),
    // odd -> v[50:51]=(d2,d3), ascending J == reference partial order);
    // combine (d0+d1)+(d2+d3); d = fma(-2, dot, A+bq); strict-< min track.
    // First op per acc is v_pk_mul == fma(a,b,0) (only +-0 sign can differ,
    // provably cannot change d or the comparison).
    asm volatile(
        "s_mov_b64 s[98:99], %[ptr]\n\t"
        "s_mov_b32 s97, %[n0]\n\t"
        "s_mov_b32 s100, %[ne]\n\t"
        "1:\n\t"
        "s_load_dwordx16 s[32:47], s[98:99], 0x0\n\t"
        "s_load_dwordx16 s[48:63], s[98:99], 0x40\n\t"
        "s_load_dwordx16 s[64:79], s[98:99], 0x80\n\t"
        "s_load_dwordx16 s[80:95], s[98:99], 0xc0\n\t"
        "s_load_dword s96, s[98:99], 0x100\n\t"
        "s_waitcnt lgkmcnt(0)\n\t"
        "v_pk_mul_f32 v[48:49], %[z0], s[32:33]\n\t"
        "v_pk_mul_f32 v[50:51], %[z1], s[34:35]\n\t"
        "v_pk_fma_f32 v[48:49], %[z2], s[36:37], v[48:49]\n\t"
        "v_pk_fma_f32 v[50:51], %[z3], s[38:39], v[50:51]\n\t"
        "v_pk_fma_f32 v[48:49], %[z4], s[40:41], v[48:49]\n\t"
        "v_pk_fma_f32 v[50:51], %[z5], s[42:43], v[50:51]\n\t"
        "v_pk_fma_f32 v[48:49], %[z6], s[44:45], v[48:49]\n\t"
        "v_pk_fma_f32 v[50:51], %[z7], s[46:47], v[50:51]\n\t"
        "v_pk_fma_f32 v[48:49], %[z8], s[48:49], v[48:49]\n\t"
        "v_pk_fma_f32 v[50:51], %[z9], s[50:51], v[50:51]\n\t"
        "v_pk_fma_f32 v[48:49], %[z10], s[52:53], v[48:49]\n\t"
        "v_pk_fma_f32 v[50:51], %[z11], s[54:55], v[50:51]\n\t"
        "v_pk_fma_f32 v[48:49], %[z12], s[56:57], v[48:49]\n\t"
        "v_pk_fma_f32 v[50:51], %[z13], s[58:59], v[50:51]\n\t"
        "v_pk_fma_f32 v[48:49], %[z14], s[60:61], v[48:49]\n\t"
        "v_pk_fma_f32 v[50:51], %[z15], s[62:63], v[50:51]\n\t"
        "v_pk_fma_f32 v[48:49], %[z16], s[64:65], v[48:49]\n\t"
        "v_pk_fma_f32 v[50:51], %[z17], s[66:67], v[50:51]\n\t"
        "v_pk_fma_f32 v[48:49], %[z18], s[68:69], v[48:49]\n\t"
        "v_pk_fma_f32 v[50:51], %[z19], s[70:71], v[50:51]\n\t"
        "v_pk_fma_f32 v[48:49], %[z20], s[72:73], v[48:49]\n\t"
        "v_pk_fma_f32 v[50:51], %[z21], s[74:75], v[50:51]\n\t"
        "v_pk_fma_f32 v[48:49], %[z22], s[76:77], v[48:49]\n\t"
        "v_pk_fma_f32 v[50:51], %[z23], s[78:79], v[50:51]\n\t"
        "v_pk_fma_f32 v[48:49], %[z24], s[80:81], v[48:49]\n\t"
        "v_pk_fma_f32 v[50:51], %[z25], s[82:83], v[50:51]\n\t"
        "v_pk_fma_f32 v[48:49], %[z26], s[84:85], v[48:49]\n\t"
        "v_pk_fma_f32 v[50:51], %[z27], s[86:87], v[50:51]\n\t"
        "v_pk_fma_f32 v[48:49], %[z28], s[88:89], v[48:49]\n\t"
        "v_pk_fma_f32 v[50:51], %[z29], s[90:91], v[50:51]\n\t"
        "v_pk_fma_f32 v[48:49], %[z30], s[92:93], v[48:49]\n\t"
        "v_pk_fma_f32 v[50:51], %[z31], s[94:95], v[50:51]\n\t"
        "v_add_f32 v52, v48, v49\n\t"
        "v_add_f32 v53, v50, v51\n\t"
        "v_add_f32 v52, v52, v53\n\t"
        "v_add_f32 v53, s96, %[A]\n\t"
        "v_fma_f32 v54, -2.0, v52, v53\n\t"
        "v_mov_b32 v55, s97\n\t"
        "v_cmp_lt_f32 vcc, v54, %[best]\n\t"
        "v_cndmask_b32 %[best], %[best], v54, vcc\n\t"
        "v_cndmask_b32 %[bidx], %[bidx], v55, vcc\n\t"
        "s_add_u32 s98, s98, 272\n\t"
        "s_addc_u32 s99, s99, 0\n\t"
        "s_add_u32 s97, s97, 1\n\t"
        "s_cmp_lt_u32 s97, s100\n\t"
        "s_cbranch_scc1 1b\n\t"
        : [best]"+v"(best), [bidx]"+v"(bidx)
        : [z0]"v"(Z0),  [z1]"v"(Z1),  [z2]"v"(Z2),  [z3]"v"(Z3),
          [z4]"v"(Z4),  [z5]"v"(Z5),  [z6]"v"(Z6),  [z7]"v"(Z7),
          [z8]"v"(Z8),  [z9]"v"(Z9),  [z10]"v"(Z10), [z11]"v"(Z11),
          [z12]"v"(Z12), [z13]"v"(Z13), [z14]"v"(Z14), [z15]"v"(Z15),
          [z16]"v"(Z16), [z17]"v"(Z17), [z18]"v"(Z18), [z19]"v"(Z19),
          [z20]"v"(Z20), [z21]"v"(Z21), [z22]"v"(Z22), [z23]"v"(Z23),
          [z24]"v"(Z24), [z25]"v"(Z25), [z26]"v"(Z26), [z27]"v"(Z27),
          [z28]"v"(Z28), [z29]"v"(Z29), [z30]"v"(Z30), [z31]"v"(Z31),
          [A]"v"(A), [ptr]"s"(rowPtr), [n0]"s"(c0i), [ne]"s"(cend)
        : SCLOBBERS,
          "v48","v49","v50","v51","v52","v53","v54","v55",
          "vcc","scc","memory");

    // d >= 0 always so float order == uint order; low 32 bits = idx so
    // equal-d ties pick the smaller index (first-occurrence argmin).
    unsigned long long pk =
        ((unsigned long long)__float_as_uint(best) << 32) | (unsigned)bidx;
    atomicMin(&packed[t], pk);
}

// ---- unpack chunk-combined argmin, emit idx + counts ----------------------
__global__ __launch_bounds__(256) void kFinish(const unsigned long long* __restrict__ packed,
                                               float* __restrict__ outIdxF,
                                               int* __restrict__ wsIdx,
                                               unsigned* __restrict__ counts) {
    int t = blockIdx.x * 256 + threadIdx.x;
    int idx = (int)(unsigned)(packed[t] & 0xFFFFFFFFull);
    outIdxF[t] = (float)idx;
    wsIdx[t]   = idx;
    atomicAdd(&counts[idx], 1u);
}

// ---- exclusive prefix sum of counts -> bucket offsets ---------------------
__global__ __launch_bounds__(256) void kOffsets(const unsigned* __restrict__ counts,
                                                unsigned* __restrict__ offsets) {
    __shared__ unsigned psum[256];
    int tid = threadIdx.x;
    unsigned local[16];
    unsigned s = 0;
#pragma unroll
    for (int j = 0; j < 16; ++j) { local[j] = s; s += counts[tid * 16 + j]; }
    psum[tid] = s;
    __syncthreads();
    unsigned base = 0;
    for (int i = 0; i < tid; ++i) base += psum[i];
#pragma unroll
    for (int j = 0; j < 16; ++j) offsets[tid * 16 + j] = base + local[j];
}

// ---- scatter token ids into per-code buckets ------------------------------
__global__ __launch_bounds__(256) void kScatter(const int* __restrict__ wsIdx,
                                                const unsigned* __restrict__ offsets,
                                                unsigned* __restrict__ cursor,
                                                int* __restrict__ bucket) {
    int t = blockIdx.x * 256 + threadIdx.x;
    int idx = wsIdx[t];
    unsigned pos = atomicAdd(&cursor[idx], 1u);
    bucket[offsets[idx] + pos] = t;
}

// ---- streaming epilogue: gather, straight-through out, loss partials ------
__global__ __launch_bounds__(256) void kEpilogue(const float* __restrict__ z,
                                                 const float* __restrict__ e,
                                                 const int* __restrict__ wsIdx,
                                                 float* __restrict__ out,
                                                 double* __restrict__ lossPart) {
    __shared__ double lp[4];
    long g = (long)blockIdx.x * 256 + threadIdx.x;   // 0 .. 4194303 (z-linear)
    int b = (int)(g >> 20);
    int r = (int)(g & 1048575);
    int k = r >> 14;
    int s = r & 16383;
    int t = (b << 14) | s;

    float zv = z[g];
    int n = wsIdx[t];
    float eq = e[(n << 6) + k];
    float diff = eq - zv;            // fl(z_q - zp)
    out[g] = zv + diff;              // fl(zp + fl(z_q - zp))  (straight-through)

    double sq = (double)diff * (double)diff;
#pragma unroll
    for (int o = 32; o > 0; o >>= 1) sq += __shfl_down(sq, o);
    if ((threadIdx.x & 63) == 0) lp[threadIdx.x >> 6] = sq;
    __syncthreads();
    if (threadIdx.x == 0) lossPart[blockIdx.x] = (lp[0] + lp[1]) + (lp[2] + lp[3]);
}

// ---- reduce loss partials -------------------------------------------------
__global__ __launch_bounds__(256) void kLoss(const double* __restrict__ lossPart,
                                             double* __restrict__ acc) {
    __shared__ double lp[4];
    double s = 0.0;
    for (int j = 0; j < 64; ++j) s += lossPart[threadIdx.x + j * 256];
#pragma unroll
    for (int o = 32; o > 0; o >>= 1) s += __shfl_down(s, o);
    if ((threadIdx.x & 63) == 0) lp[threadIdx.x >> 6] = s;
    __syncthreads();
    if (threadIdx.x == 0) acc[0] = (lp[0] + lp[1]) + (lp[2] + lp[3]);
}

// ---- EMA part 1: new_cs, n-sum, perplexity partial ------------------------
__global__ __launch_bounds__(256) void kEma1(const float* __restrict__ cs,
                                             const unsigned* __restrict__ counts,
                                             float* __restrict__ outNcs,
                                             double* __restrict__ acc) {
    int n = blockIdx.x * 256 + threadIdx.x;
    float cf = (float)counts[n];
    float p1 = cs[n] * 0.99f;
    float p2 = 0.01f * cf;
    float ncs = p1 + p2;
    outNcs[n] = ncs;
    float p = cf * (1.0f / 65536.0f);          // exact (pow2 divide)
    float term = p * logf(p + 1e-10f);
    double dn = (double)ncs, dt = (double)term;
#pragma unroll
    for (int o = 32; o > 0; o >>= 1) { dn += __shfl_down(dn, o); dt += __shfl_down(dt, o); }
    if ((threadIdx.x & 63) == 0) {
        atomicAdd(&acc[1], dn);
        atomicAdd(&acc[2], dt);
    }
}

// ---- per-code bucket gather: embed_sum -> new_ea, new_embed; scalars ------
__global__ __launch_bounds__(64) void kEsumEma2(const float* __restrict__ z,
                                                const float* __restrict__ ea,
                                                const int* __restrict__ bucket,
                                                const unsigned* __restrict__ offsets,
                                                const unsigned* __restrict__ counts,
                                                const float* __restrict__ ncsArr,
                                                const double* __restrict__ acc,
                                                float* __restrict__ outNemb,
                                                float* __restrict__ outNea,
                                                float* __restrict__ outLoss,
                                                float* __restrict__ outPerp) {
    int n = blockIdx.x;              // code id
    int k = threadIdx.x;             // dim
    unsigned off = offsets[n];
    unsigned cnt = counts[n];
    float es = 0.f;
    for (unsigned i = 0; i < cnt; ++i) {
        int t = bucket[off + i];
        int b = t >> 14;
        int s = t & 16383;
        es += z[(long)b * 1048576 + k * 16384 + s];
    }
    float nea = ea[(n << 6) + k] * 0.99f + 0.01f * es;
    outNea[(n << 6) + k] = nea;
    float nt = (float)acc[1];
    float ncs = ncsArr[n];
    float sc = ((ncs + 1e-5f) / (nt + 0.04096f)) * nt;
    outNemb[(n << 6) + k] = nea / sc;
    if (n == 0 && k == 0) {
        double m = acc[0] / 4194304.0;
        outLoss[0] = 0.25f * (float)m;
        outPerp[0] = (float)exp(-acc[2]);
    }
}

extern "C" void kernel_launch(void* const* d_in, const int* in_sizes, int n_in,
                              void* d_out, int out_size, void* d_ws, size_t ws_size,
                              hipStream_t stream) {
    const float* z  = (const float*)d_in[0];
    const float* ew = (const float*)d_in[1];
    const float* cs = (const float*)d_in[2];
    const float* ea = (const float*)d_in[3];
    float* out = (float*)d_out;
    char* ws = (char*)d_ws;

    double*   acc    = (double*)(ws + W_ACC);
    unsigned* counts = (unsigned*)(ws + W_CNT);
    unsigned* cursor = (unsigned*)(ws + W_CUR);
    unsigned* offs   = (unsigned*)(ws + W_OFF);
    int*      wsIdx  = (int*)(ws + W_IDX);
    int*      bucket = (int*)(ws + W_BKT);
    double*   lossP  = (double*)(ws + W_LOSSP);
    unsigned long long* packed = (unsigned long long*)(ws + W_PKD);
    float*    aug    = (float*)(ws + W_AUG);

    hipMemsetAsync(ws, 0, W_ZERO_BYTES, stream);
    hipMemsetAsync(ws + W_PKD, 0xFF, W_PKD_BYTES, stream);
    kAug<<<NE / 256, 256, 0, stream>>>(ew, aug);
    kArgmin<<<(NTOK / 256) * NCHUNK, 256, 0, stream>>>(z, aug, packed);
    kFinish<<<NTOK / 256, 256, 0, stream>>>(packed, out + O_IDX, wsIdx, counts);
    kOffsets<<<1, 256, 0, stream>>>(counts, offs);
    kScatter<<<NTOK / 256, 256, 0, stream>>>(wsIdx, offs, cursor, bucket);
    kEpilogue<<<16384, 256, 0, stream>>>(z, ew, wsIdx, out + O_OUT, lossP);
    kLoss<<<1, 256, 0, stream>>>(lossP, acc);
    kEma1<<<NE / 256, 256, 0, stream>>>(cs, counts, out + O_NCS, acc);
    kEsumEma2<<<NE, 64, 0, stream>>>(z, ea, bucket, offs, counts, out + O_NCS, acc,
                                     out + O_NEMB, out + O_NEA,
                                     out + O_LOSS, out + O_PERP);
}